// Round 3
// baseline (2119.862 us; speedup 1.0000x reference)
//
#include <hip/hip_runtime.h>

#define T_TOK 8192
#define HDIM  2048
#define NEXP  32
#define IDIM  1024

#define BM 128
#define BN 128
#define BK 64
#define CAP (T_TOK*2 + NEXP*BM)   // 20480 max padded rows
#define MAX_RT (CAP/BM)           // 160 row tiles max

typedef __attribute__((ext_vector_type(8))) short bh8;   // 8 bf16 (4 VGPR) MFMA A/B frag
typedef __attribute__((ext_vector_type(4))) float f4;    // MFMA C/D frag

// fp32 -> bf16 round-to-nearest-even (bit pattern)
__device__ __forceinline__ unsigned short f2bf(float f) {
    unsigned u = __builtin_bit_cast(unsigned, f);
    u += 0x7FFFu + ((u >> 16) & 1u);
    return (unsigned short)(u >> 16);
}

// swizzle for X/act buffers (row&7 based; matches gload16 pre-swizzled source trick)
__device__ __forceinline__ int swz(int row, int kb) {
    return row * 128 + (kb ^ ((row & 7) << 4));
}
// swizzle for reg-staged W buffers: writes are 4-consecutive-n per lane, so the
// varying bits are n>>2. Write side conflict-free; read side 2-way (free, m136).
__device__ __forceinline__ int swzW(int row, int kb) {
    return row * 128 + (kb ^ (((row >> 2) & 7) << 4));
}

// async 16B global->LDS (dest = wave-uniform base + lane*16, source per-lane)
__device__ __forceinline__ void gload16(const void* g, void* l) {
    __builtin_amdgcn_global_load_lds(
        (const __attribute__((address_space(1))) unsigned int*)g,
        (__attribute__((address_space(3))) unsigned int*)l,
        16, 0, 0);
}

// ---------------- routing ----------------

__device__ __forceinline__ void top2(const float* __restrict__ l,
                                     int& b1, float& v1, int& b2, float& v2) {
    v1 = -1e30f; b1 = 0;
#pragma unroll
    for (int e = 0; e < NEXP; ++e) { float v = l[e]; if (v > v1) { v1 = v; b1 = e; } }
    v2 = -1e30f; b2 = 0;
#pragma unroll
    for (int e = 0; e < NEXP; ++e) { if (e == b1) continue; float v = l[e]; if (v > v2) { v2 = v; b2 = e; } }
}

__global__ void route_count_kernel(const float* __restrict__ logits, int* __restrict__ counts) {
    int t = blockIdx.x * blockDim.x + threadIdx.x;
    if (t >= T_TOK) return;
    int b1, b2; float v1, v2;
    top2(logits + (size_t)t * NEXP, b1, v1, b2, v2);
    atomicAdd(&counts[b1], 1);
    atomicAdd(&counts[b2], 1);
}

__global__ void offsets_kernel(const int* __restrict__ counts, int* __restrict__ offs) {
    if (threadIdx.x == 0) {
        int o = 0;
        for (int e = 0; e < NEXP; ++e) { offs[e] = o; o += (counts[e] + BM - 1) & ~(BM - 1); }
        offs[NEXP] = o;
    }
}

__global__ void route_scatter_kernel(const float* __restrict__ logits,
                                     const float* __restrict__ scale,
                                     const int* __restrict__ offs,
                                     int* __restrict__ cursor,
                                     int* __restrict__ row_tok,
                                     float* __restrict__ row_w) {
    int t = blockIdx.x * blockDim.x + threadIdx.x;
    if (t >= T_TOK) return;
    int b1, b2; float v1, v2;
    top2(logits + (size_t)t * NEXP, b1, v1, b2, v2);
    float e2 = expf(v2 - v1);
    float inv = 1.0f / (1.0f + e2);
    float w1 = scale[b1] * inv;
    float w2 = scale[b2] * e2 * inv;
    int p1 = offs[b1] + atomicAdd(&cursor[b1], 1);
    row_tok[p1] = t; row_w[p1] = w1;
    int p2 = offs[b2] + atomicAdd(&cursor[b2], 1);
    row_tok[p2] = t; row_w[p2] = w2;
}

// hs fp32 -> bf16 streaming convert
__global__ void cvt_hs_kernel(const float* __restrict__ in, unsigned short* __restrict__ out) {
    size_t i = ((size_t)blockIdx.x * 256 + threadIdx.x) * 8;
    float4 a = *(const float4*)(in + i);
    float4 b = *(const float4*)(in + i + 4);
    bh8 v;
    v[0] = (short)f2bf(a.x); v[1] = (short)f2bf(a.y);
    v[2] = (short)f2bf(a.z); v[3] = (short)f2bf(a.w);
    v[4] = (short)f2bf(b.x); v[5] = (short)f2bf(b.y);
    v[6] = (short)f2bf(b.z); v[7] = (short)f2bf(b.w);
    *(bh8*)(out + i) = v;
}

// ============ GEMM1: act = gelu(X@Wg) * (X@Wu), fused fp32-W convert ============
// Block: 128 rows x 128 cols. Waves 2x2 (64r x 64c each, for both G and U).
// X: bf16 via gload16, double-buffered LDS. Wg/Wu: fp32 [k][n] -> reg transpose
// -> bf16 swizzled [n][k] LDS, single-buffered (regs are the second buffer).
__launch_bounds__(256, 2)
__global__ void gemm1f_kernel(const unsigned short* __restrict__ hsb,
                              const float* __restrict__ wg,
                              const float* __restrict__ wu,
                              const int* __restrict__ offs,
                              const int* __restrict__ row_tok,
                              unsigned short* __restrict__ act) {
    __shared__ char lds[65536];
    char* Xb0 = lds;            // 16 KB
    char* Xb1 = lds + 16384;    // 16 KB
    char* Gb  = lds + 32768;    // 16 KB
    char* Ub  = lds + 49152;    // 16 KB

    int rt = blockIdx.x >> 3;
    int nt = blockIdx.x & 7;
    int total = offs[NEXP];
    if (rt * BM >= total) return;
    int e = 0;
    while (offs[e + 1] <= rt * BM) e++;

    int tid = threadIdx.x, l = tid & 63, wv = tid >> 6;
    int wm = wv >> 1, wn = wv & 1;

    // ---- X staging (gload16, pre-swizzled source) ----
    unsigned srcChunk = ((l & 7) * 16) ^ ((l >> 3) << 4);
    unsigned xoff[4];
#pragma unroll
    for (int i = 0; i < 4; ++i) {
        int r = i * 32 + wv * 8 + (l >> 3);
        int tok = row_tok[rt * BM + r];
        if (tok < 0) tok = 0;
        xoff[i] = (unsigned)tok * (HDIM * 2) + srcChunk;
    }
    const char* hsc = (const char*)hsb;

    // ---- W staging (reg transpose) ----
    int g32 = tid & 31, kc8 = tid >> 5;   // n-group (4 cols), k-chunk (8 rows)
    const float* wgp = wg + (size_t)e * HDIM * IDIM + (size_t)kc8 * 8 * IDIM + nt * BN + g32 * 4;
    const float* wup = wu + (size_t)e * HDIM * IDIM + (size_t)kc8 * 8 * IDIM + nt * BN + g32 * 4;
    float4 wGr[8], wUr[8];

    f4 accG[4][4], accU[4][4];
#pragma unroll
    for (int mi = 0; mi < 4; ++mi)
#pragma unroll
        for (int ni = 0; ni < 4; ++ni) { accG[mi][ni] = (f4)0.0f; accU[mi][ni] = (f4)0.0f; }

#define LOADW1(KT) {                                                        \
    size_t kb_ = (size_t)(KT) * 64;                                         \
    _Pragma("unroll")                                                       \
    for (int j = 0; j < 8; ++j) {                                           \
        wGr[j] = *(const float4*)(wgp + (kb_ + j) * IDIM);                  \
        wUr[j] = *(const float4*)(wup + (kb_ + j) * IDIM);                  \
    } }

#define WRITEW1() {                                                         \
    _Pragma("unroll")                                                       \
    for (int c = 0; c < 4; ++c) {                                           \
        int n_ = g32 * 4 + c;                                               \
        int wb_ = n_ * 128 + ((kc8 * 16) ^ ((g32 & 7) << 4));               \
        bh8 pg, pu;                                                         \
        _Pragma("unroll")                                                   \
        for (int j = 0; j < 8; ++j) {                                       \
            float gg = (c == 0) ? wGr[j].x : (c == 1) ? wGr[j].y : (c == 2) ? wGr[j].z : wGr[j].w; \
            float uu = (c == 0) ? wUr[j].x : (c == 1) ? wUr[j].y : (c == 2) ? wUr[j].z : wUr[j].w; \
            pg[j] = (short)f2bf(gg);                                        \
            pu[j] = (short)f2bf(uu);                                        \
        }                                                                   \
        *(bh8*)(Gb + wb_) = pg;                                             \
        *(bh8*)(Ub + wb_) = pu;                                             \
    } }

#define LOADX1(KT, XB) {                                                    \
    unsigned kby_ = (unsigned)(KT) * 128;                                   \
    _Pragma("unroll")                                                       \
    for (int i = 0; i < 4; ++i)                                             \
        gload16(hsc + (size_t)xoff[i] + kby_, (XB) + i * 4096 + wv * 1024); \
    }

    // prologue: tile 0
    LOADW1(0);
    LOADX1(0, Xb0);
    WRITEW1();
    __syncthreads();

    for (int kt = 0; kt < HDIM / BK; ++kt) {
        char* cur = (kt & 1) ? Xb1 : Xb0;
        char* nxt = (kt & 1) ? Xb0 : Xb1;
        if (kt < HDIM / BK - 1) {
            LOADW1(kt + 1);
            LOADX1(kt + 1, nxt);
        }
        // compute on tile kt
#pragma unroll
        for (int ks = 0; ks < 2; ++ks) {
            int kb = ks * 64 + ((l >> 4) << 4);
            bh8 a[4], g[4], u[4];
#pragma unroll
            for (int mi = 0; mi < 4; ++mi)
                a[mi] = *(const bh8*)(cur + swz(wm * 64 + mi * 16 + (l & 15), kb));
#pragma unroll
            for (int ni = 0; ni < 4; ++ni) {
                int nr = wn * 64 + ni * 16 + (l & 15);
                g[ni] = *(const bh8*)(Gb + swzW(nr, kb));
                u[ni] = *(const bh8*)(Ub + swzW(nr, kb));
            }
#pragma unroll
            for (int mi = 0; mi < 4; ++mi)
#pragma unroll
                for (int ni = 0; ni < 4; ++ni) {
                    accG[mi][ni] = __builtin_amdgcn_mfma_f32_16x16x32_bf16(a[mi], g[ni], accG[mi][ni], 0, 0, 0);
                    accU[mi][ni] = __builtin_amdgcn_mfma_f32_16x16x32_bf16(a[mi], u[ni], accU[mi][ni], 0, 0, 0);
                }
        }
        __syncthreads();                 // W reads done; drains vmem issued ~compute-start
        if (kt < HDIM / BK - 1) WRITEW1();
        __syncthreads();                 // lgkm only
    }

    // epilogue: gelu(g)*u -> bf16 act, pre-swizzled byte layout
    char* actc = (char*)act;
#pragma unroll
    for (int mi = 0; mi < 4; ++mi) {
#pragma unroll
        for (int i = 0; i < 4; ++i) {
            int r = rt * BM + wm * 64 + mi * 16 + ((l >> 4) << 2) + i;
            size_t rowbase = (size_t)r * (IDIM * 2);
            int rs = (r & 7) << 4;
#pragma unroll
            for (int ni = 0; ni < 4; ++ni) {
                int col = nt * BN + wn * 64 + ni * 16 + (l & 15);
                float gv = accG[mi][ni][i], uv = accU[mi][ni][i];
                float gl = 0.5f * gv * (1.0f + erff(gv * 0.70710678118654752f));
                *(unsigned short*)(actc + rowbase + ((col * 2) ^ rs)) = f2bf(gl * uv);
            }
        }
    }
#undef LOADW1
#undef WRITEW1
#undef LOADX1
}

// ============ GEMM2: out[tok] += w * (act @ Wd), fused fp32-W convert ============
// Block 128 rows x 128 cols, waves 2x2 (64x64). act: gload16 dbuf; Wd: reg-staged.
__launch_bounds__(256, 3)
__global__ void gemm2f_kernel(const unsigned short* __restrict__ act,
                              const float* __restrict__ wd,
                              const int* __restrict__ offs,
                              const int* __restrict__ row_tok,
                              const float* __restrict__ row_w,
                              float* __restrict__ out) {
    __shared__ char lds[49152];
    char* Xb0 = lds;            // 16 KB
    char* Xb1 = lds + 16384;    // 16 KB
    char* Db  = lds + 32768;    // 16 KB

    int rt = blockIdx.x >> 4;
    int nt = blockIdx.x & 15;   // 2048 / 128
    int total = offs[NEXP];
    if (rt * BM >= total) return;
    int e = 0;
    while (offs[e + 1] <= rt * BM) e++;

    int tid = threadIdx.x, l = tid & 63, wv = tid >> 6;
    int wm = wv >> 1, wn = wv & 1;

    unsigned aoff[4];
#pragma unroll
    for (int i = 0; i < 4; ++i) {
        int r = i * 32 + wv * 8 + (l >> 3);
        aoff[i] = (unsigned)(rt * BM + r) * (IDIM * 2) + (l & 7) * 16;  // act pre-swizzled: linear
    }
    const char* actc = (const char*)act;

    int g32 = tid & 31, kc8 = tid >> 5;
    const float* wdp = wd + (size_t)e * IDIM * HDIM + (size_t)kc8 * 8 * HDIM + nt * BN + g32 * 4;
    float4 wDr[8];

    f4 acc[4][4];
#pragma unroll
    for (int mi = 0; mi < 4; ++mi)
#pragma unroll
        for (int ni = 0; ni < 4; ++ni) acc[mi][ni] = (f4)0.0f;

#define LOADW2(KT) {                                                        \
    size_t kb_ = (size_t)(KT) * 64;                                         \
    _Pragma("unroll")                                                       \
    for (int j = 0; j < 8; ++j)                                             \
        wDr[j] = *(const float4*)(wdp + (kb_ + j) * HDIM);                  \
    }

#define WRITEW2() {                                                         \
    _Pragma("unroll")                                                       \
    for (int c = 0; c < 4; ++c) {                                           \
        int n_ = g32 * 4 + c;                                               \
        int wb_ = n_ * 128 + ((kc8 * 16) ^ ((g32 & 7) << 4));               \
        bh8 pd;                                                             \
        _Pragma("unroll")                                                   \
        for (int j = 0; j < 8; ++j) {                                       \
            float dd = (c == 0) ? wDr[j].x : (c == 1) ? wDr[j].y : (c == 2) ? wDr[j].z : wDr[j].w; \
            pd[j] = (short)f2bf(dd);                                        \
        }                                                                   \
        *(bh8*)(Db + wb_) = pd;                                             \
    } }

#define LOADX2(KT, XB) {                                                    \
    unsigned kby_ = (unsigned)(KT) * 128;                                   \
    _Pragma("unroll")                                                       \
    for (int i = 0; i < 4; ++i)                                             \
        gload16(actc + (size_t)aoff[i] + kby_, (XB) + i * 4096 + wv * 1024);\
    }

    LOADW2(0);
    LOADX2(0, Xb0);
    WRITEW2();
    __syncthreads();

    for (int kt = 0; kt < IDIM / BK; ++kt) {
        char* cur = (kt & 1) ? Xb1 : Xb0;
        char* nxt = (kt & 1) ? Xb0 : Xb1;
        if (kt < IDIM / BK - 1) {
            LOADW2(kt + 1);
            LOADX2(kt + 1, nxt);
        }
#pragma unroll
        for (int ks = 0; ks < 2; ++ks) {
            int kb = ks * 64 + ((l >> 4) << 4);
            bh8 a[4], b[4];
#pragma unroll
            for (int mi = 0; mi < 4; ++mi)
                a[mi] = *(const bh8*)(cur + swz(wm * 64 + mi * 16 + (l & 15), kb));
#pragma unroll
            for (int ni = 0; ni < 4; ++ni)
                b[ni] = *(const bh8*)(Db + swzW(wn * 64 + ni * 16 + (l & 15), kb));
#pragma unroll
            for (int mi = 0; mi < 4; ++mi)
#pragma unroll
                for (int ni = 0; ni < 4; ++ni)
                    acc[mi][ni] = __builtin_amdgcn_mfma_f32_16x16x32_bf16(a[mi], b[ni], acc[mi][ni], 0, 0, 0);
        }
        __syncthreads();
        if (kt < IDIM / BK - 1) WRITEW2();
        __syncthreads();
    }

    // epilogue: scale by routing weight, atomic accumulate
#pragma unroll
    for (int mi = 0; mi < 4; ++mi) {
#pragma unroll
        for (int i = 0; i < 4; ++i) {
            int r = rt * BM + wm * 64 + mi * 16 + ((l >> 4) << 2) + i;
            int tok = row_tok[r];
            if (tok < 0) continue;
            float w = row_w[r];
            float* op = out + (size_t)tok * HDIM + nt * BN + wn * 64 + (l & 15);
#pragma unroll
            for (int ni = 0; ni < 4; ++ni)
                atomicAdd(op + ni * 16, acc[mi][ni][i] * w);
        }
    }
#undef LOADW2
#undef WRITEW2
#undef LOADX2
}

// ---------------- launch ----------------
// ws layout:
//   [0,512): counts(128) | cursor(128) | offs(132)
//   512:           row_tok  CAP*4
//   512+CAP*4:     row_w    CAP*4
//   512+CAP*8:     act      CAP*IDIM*2   (41.9 MB)
//   +actB:         hs_bf16  T*H*2        (33.6 MB)
//   total ~75.7 MB

extern "C" void kernel_launch(void* const* d_in, const int* in_sizes, int n_in,
                              void* d_out, int out_size, void* d_ws, size_t ws_size,
                              hipStream_t stream) {
    const float* hs     = (const float*)d_in[0];
    const float* logits = (const float*)d_in[1];
    const float* scale  = (const float*)d_in[2];
    const float* wg     = (const float*)d_in[3];
    const float* wu     = (const float*)d_in[4];
    const float* wd     = (const float*)d_in[5];
    float* out = (float*)d_out;

    char* ws = (char*)d_ws;
    int*   counts  = (int*)ws;
    int*   cursor  = counts + 32;
    int*   offs    = cursor + 32;
    int*   row_tok = (int*)(ws + 512);
    float* row_w   = (float*)(ws + 512 + (size_t)CAP * 4);
    unsigned short* act = (unsigned short*)(ws + 512 + (size_t)CAP * 8);
    size_t actB = (size_t)CAP * IDIM * 2;
    unsigned short* hsb = (unsigned short*)(ws + 512 + (size_t)CAP * 8 + actB);

    hipMemsetAsync(counts, 0, 512, stream);
    hipMemsetAsync(row_tok, 0xFF, (size_t)CAP * 4, stream);
    hipMemsetAsync(out, 0, (size_t)out_size * sizeof(float), stream);

    route_count_kernel<<<T_TOK / 256, 256, 0, stream>>>(logits, counts);
    offsets_kernel<<<1, 64, 0, stream>>>(counts, offs);
    route_scatter_kernel<<<T_TOK / 256, 256, 0, stream>>>(logits, scale, offs, cursor, row_tok, row_w);
    cvt_hs_kernel<<<(T_TOK * HDIM) / (256 * 8), 256, 0, stream>>>(hs, hsb);
    gemm1f_kernel<<<MAX_RT * 8, 256, 0, stream>>>(hsb, wg, wu, offs, row_tok, act);
    gemm2f_kernel<<<MAX_RT * 16, 256, 0, stream>>>(act, wd, offs, row_tok, row_w, out);
}

// Round 4
// 748.162 us; speedup vs baseline: 2.8334x; 2.8334x over previous
//
#include <hip/hip_runtime.h>

#define T_TOK 8192
#define HDIM  2048
#define NEXP  32
#define IDIM  1024

#define BM 128
#define BK 64
#define CAP (T_TOK*2 + NEXP*BM)   // 20480 max padded rows
#define MAX_RT (CAP/BM)           // 160 row tiles max

typedef __attribute__((ext_vector_type(8))) short bh8;   // 8 bf16 (4 VGPR) MFMA A/B frag
typedef __attribute__((ext_vector_type(4))) float f4;    // MFMA C/D frag

// fp32 -> bf16 round-to-nearest-even (bit pattern)
__device__ __forceinline__ unsigned short f2bf(float f) {
    unsigned u = __builtin_bit_cast(unsigned, f);
    u += 0x7FFFu + ((u >> 16) & 1u);
    return (unsigned short)(u >> 16);
}

// XOR swizzle: 128-byte LDS rows, byte ^= (row&7)<<4.  (round-1/2 proven: 0 conflicts)
__device__ __forceinline__ int swz(int row, int kb) {
    return row * 128 + (kb ^ ((row & 7) << 4));
}

// async 16B global->LDS (dest = wave-uniform base + lane*16, source per-lane)
__device__ __forceinline__ void gload16(const void* g, void* l) {
    __builtin_amdgcn_global_load_lds(
        (const __attribute__((address_space(1))) unsigned int*)g,
        (__attribute__((address_space(3))) unsigned int*)l,
        16, 0, 0);
}

// ---------------- routing ----------------

__device__ __forceinline__ void top2(const float* __restrict__ l,
                                     int& b1, float& v1, int& b2, float& v2) {
    v1 = -1e30f; b1 = 0;
#pragma unroll
    for (int e = 0; e < NEXP; ++e) { float v = l[e]; if (v > v1) { v1 = v; b1 = e; } }
    v2 = -1e30f; b2 = 0;
#pragma unroll
    for (int e = 0; e < NEXP; ++e) { if (e == b1) continue; float v = l[e]; if (v > v2) { v2 = v; b2 = e; } }
}

__global__ void route_count_kernel(const float* __restrict__ logits, int* __restrict__ counts) {
    int t = blockIdx.x * blockDim.x + threadIdx.x;
    if (t >= T_TOK) return;
    int b1, b2; float v1, v2;
    top2(logits + (size_t)t * NEXP, b1, v1, b2, v2);
    atomicAdd(&counts[b1], 1);
    atomicAdd(&counts[b2], 1);
}

__global__ void offsets_kernel(const int* __restrict__ counts, int* __restrict__ offs) {
    if (threadIdx.x == 0) {
        int o = 0;
        for (int e = 0; e < NEXP; ++e) { offs[e] = o; o += (counts[e] + BM - 1) & ~(BM - 1); }
        offs[NEXP] = o;
    }
}

__global__ void route_scatter_kernel(const float* __restrict__ logits,
                                     const float* __restrict__ scale,
                                     const int* __restrict__ offs,
                                     int* __restrict__ cursor,
                                     int* __restrict__ row_tok,
                                     float* __restrict__ row_w) {
    int t = blockIdx.x * blockDim.x + threadIdx.x;
    if (t >= T_TOK) return;
    int b1, b2; float v1, v2;
    top2(logits + (size_t)t * NEXP, b1, v1, b2, v2);
    float e2 = expf(v2 - v1);
    float inv = 1.0f / (1.0f + e2);
    float w1 = scale[b1] * inv;
    float w2 = scale[b2] * e2 * inv;
    int p1 = offs[b1] + atomicAdd(&cursor[b1], 1);
    row_tok[p1] = t; row_w[p1] = w1;
    int p2 = offs[b2] + atomicAdd(&cursor[b2], 1);
    row_tok[p2] = t; row_w[p2] = w2;
}

// hs fp32 -> bf16 streaming convert
__global__ void cvt_hs_kernel(const float* __restrict__ in, unsigned short* __restrict__ out) {
    size_t i = ((size_t)blockIdx.x * 256 + threadIdx.x) * 8;
    float4 a = *(const float4*)(in + i);
    float4 b = *(const float4*)(in + i + 4);
    bh8 v;
    v[0] = (short)f2bf(a.x); v[1] = (short)f2bf(a.y);
    v[2] = (short)f2bf(a.z); v[3] = (short)f2bf(a.w);
    v[4] = (short)f2bf(b.x); v[5] = (short)f2bf(b.y);
    v[6] = (short)f2bf(b.z); v[7] = (short)f2bf(b.w);
    *(bh8*)(out + i) = v;
}

// ============ GEMM1: act = gelu(X@Wg) * (X@Wu), fused fp32-W convert ============
// Block: 128 rows x 64 cols. 4 waves stacked in m (32 rows each, all 64 cols).
// X: bf16 gload16, double-buffered. Wg/Wu: fp32 [k][n] -> 8x float2/thread ->
// bf16 swizzled [n][k] LDS (write rows n&7 = full spread: conflict-free).
__launch_bounds__(256, 1)
__global__ void gemm1f2_kernel(const unsigned short* __restrict__ hsb,
                               const float* __restrict__ wg,
                               const float* __restrict__ wu,
                               const int* __restrict__ offs,
                               const int* __restrict__ row_tok,
                               unsigned short* __restrict__ act) {
    __shared__ char lds[49152];
    char* Xb0 = lds;            // 16 KB (128 rows x 128B)
    char* Xb1 = lds + 16384;    // 16 KB
    char* Gb  = lds + 32768;    // 8 KB (64 rows x 128B)
    char* Ub  = lds + 40960;    // 8 KB

    int rt = blockIdx.x >> 4;
    int nt = blockIdx.x & 15;   // IDIM/64
    int total = offs[NEXP];
    if (rt * BM >= total) return;
    int e = 0;
    while (offs[e + 1] <= rt * BM) e++;

    int tid = threadIdx.x, l = tid & 63, wv = tid >> 6;

    // ---- X staging (gload16, pre-swizzled source) ----
    unsigned srcChunk = ((l & 7) * 16) ^ ((l >> 3) << 4);
    unsigned xoff[4];
#pragma unroll
    for (int i = 0; i < 4; ++i) {
        int r = i * 32 + wv * 8 + (l >> 3);
        int tok = row_tok[rt * BM + r];
        if (tok < 0) tok = 0;
        xoff[i] = (unsigned)tok * (HDIM * 2) + srcChunk;
    }
    const char* hsc = (const char*)hsb;

    // ---- W staging: thread owns cols n0,n0+1 and 8 consecutive k ----
    int nh = (tid & 31) * 2;   // n0 within 64-col tile
    int kc = tid >> 5;         // k-chunk 0..7 (8 k each)
    const float* wgp = wg + (size_t)e * HDIM * IDIM + (size_t)kc * 8 * IDIM + nt * 64 + nh;
    const float* wup = wu + (size_t)e * HDIM * IDIM + (size_t)kc * 8 * IDIM + nt * 64 + nh;
    float2 wGr[8], wUr[8];

    f4 accG[2][4], accU[2][4];
#pragma unroll
    for (int mi = 0; mi < 2; ++mi)
#pragma unroll
        for (int ni = 0; ni < 4; ++ni) { accG[mi][ni] = (f4)0.0f; accU[mi][ni] = (f4)0.0f; }

#define LOADW1(KT) {                                                        \
    _Pragma("unroll")                                                       \
    for (int j = 0; j < 8; ++j) {                                           \
        wGr[j] = *(const float2*)(wgp + ((size_t)(KT) * 64 + j) * IDIM);    \
        wUr[j] = *(const float2*)(wup + ((size_t)(KT) * 64 + j) * IDIM);    \
    } }

#define WRITEW1() {                                                         \
    _Pragma("unroll")                                                       \
    for (int r = 0; r < 2; ++r) {                                           \
        int n_ = nh + r;                                                    \
        bh8 pg, pu;                                                         \
        _Pragma("unroll")                                                   \
        for (int j = 0; j < 8; ++j) {                                       \
            pg[j] = (short)f2bf(r ? wGr[j].y : wGr[j].x);                   \
            pu[j] = (short)f2bf(r ? wUr[j].y : wUr[j].x);                   \
        }                                                                   \
        *(bh8*)(Gb + swz(n_, kc * 16)) = pg;                                \
        *(bh8*)(Ub + swz(n_, kc * 16)) = pu;                                \
    } }

#define LOADX1(KT, XB) {                                                    \
    unsigned kby_ = (unsigned)(KT) * 128;                                   \
    _Pragma("unroll")                                                       \
    for (int i = 0; i < 4; ++i)                                             \
        gload16(hsc + (size_t)xoff[i] + kby_, (XB) + i * 4096 + wv * 1024); \
    }

    LOADW1(0);
    LOADX1(0, Xb0);
    WRITEW1();
    __syncthreads();

    const int NT = HDIM / BK;
    for (int kt = 0; kt < NT; ++kt) {
        char* cur = (kt & 1) ? Xb1 : Xb0;
        char* nxt = (kt & 1) ? Xb0 : Xb1;
        if (kt < NT - 1) {
            LOADW1(kt + 1);          // fp32 W -> regs (issued early, hidden under MFMA)
            LOADX1(kt + 1, nxt);     // bf16 X -> other LDS buf
        }
#pragma unroll
        for (int ks = 0; ks < 2; ++ks) {
            int kb = ks * 64 + ((l >> 4) << 4);
            bh8 a[2], g[4], u[4];
#pragma unroll
            for (int mi = 0; mi < 2; ++mi)
                a[mi] = *(const bh8*)(cur + swz(wv * 32 + mi * 16 + (l & 15), kb));
#pragma unroll
            for (int ni = 0; ni < 4; ++ni) {
                int nr = ni * 16 + (l & 15);
                g[ni] = *(const bh8*)(Gb + swz(nr, kb));
                u[ni] = *(const bh8*)(Ub + swz(nr, kb));
            }
#pragma unroll
            for (int mi = 0; mi < 2; ++mi)
#pragma unroll
                for (int ni = 0; ni < 4; ++ni) {
                    accG[mi][ni] = __builtin_amdgcn_mfma_f32_16x16x32_bf16(a[mi], g[ni], accG[mi][ni], 0, 0, 0);
                    accU[mi][ni] = __builtin_amdgcn_mfma_f32_16x16x32_bf16(a[mi], u[ni], accU[mi][ni], 0, 0, 0);
                }
        }
        __syncthreads();             // all W-LDS reads done
        if (kt < NT - 1) {
            WRITEW1();               // convert + write next W tile
            __syncthreads();         // W tile ready; X gload16 drained by vmcnt at barrier
        }
    }

    // epilogue: gelu(g)*u -> bf16 act, pre-swizzled byte layout
    char* actc = (char*)act;
#pragma unroll
    for (int mi = 0; mi < 2; ++mi) {
#pragma unroll
        for (int i = 0; i < 4; ++i) {
            int r = rt * BM + wv * 32 + mi * 16 + ((l >> 4) << 2) + i;
            size_t rowbase = (size_t)r * (IDIM * 2);
            int rs = (r & 7) << 4;
#pragma unroll
            for (int ni = 0; ni < 4; ++ni) {
                int col = nt * 64 + ni * 16 + (l & 15);
                float gv = accG[mi][ni][i], uv = accU[mi][ni][i];
                float gl = 0.5f * gv * (1.0f + erff(gv * 0.70710678118654752f));
                *(unsigned short*)(actc + rowbase + ((col * 2) ^ rs)) = f2bf(gl * uv);
            }
        }
    }
#undef LOADW1
#undef WRITEW1
#undef LOADX1
}

// ============ GEMM2: out[tok] += w * (act @ Wd), fused fp32-W convert ============
// Block 128 rows x 64 cols, 4 waves stacked in m. act: gload16 dbuf (pre-swizzled
// rows -> linear source). Wd: fp32 reg-staged like gemm1.
__launch_bounds__(256, 1)
__global__ void gemm2f2_kernel(const unsigned short* __restrict__ act,
                               const float* __restrict__ wd,
                               const int* __restrict__ offs,
                               const int* __restrict__ row_tok,
                               const float* __restrict__ row_w,
                               float* __restrict__ out) {
    __shared__ char lds[40960];
    char* Xb0 = lds;            // 16 KB
    char* Xb1 = lds + 16384;    // 16 KB
    char* Db  = lds + 32768;    // 8 KB

    int rt = blockIdx.x >> 5;
    int nt = blockIdx.x & 31;   // HDIM/64
    int total = offs[NEXP];
    if (rt * BM >= total) return;
    int e = 0;
    while (offs[e + 1] <= rt * BM) e++;

    int tid = threadIdx.x, l = tid & 63, wv = tid >> 6;

    unsigned aoff[4];
#pragma unroll
    for (int i = 0; i < 4; ++i) {
        int r = i * 32 + wv * 8 + (l >> 3);
        aoff[i] = (unsigned)(rt * BM + r) * (IDIM * 2) + (l & 7) * 16;  // act pre-swizzled: linear
    }
    const char* actc = (const char*)act;

    int nh = (tid & 31) * 2;
    int kc = tid >> 5;
    const float* wdp = wd + (size_t)e * IDIM * HDIM + (size_t)kc * 8 * HDIM + nt * 64 + nh;
    float2 wDr[8];

    f4 acc[2][4];
#pragma unroll
    for (int mi = 0; mi < 2; ++mi)
#pragma unroll
        for (int ni = 0; ni < 4; ++ni) acc[mi][ni] = (f4)0.0f;

#define LOADW2(KT) {                                                        \
    _Pragma("unroll")                                                       \
    for (int j = 0; j < 8; ++j)                                             \
        wDr[j] = *(const float2*)(wdp + ((size_t)(KT) * 64 + j) * HDIM);    \
    }

#define WRITEW2() {                                                         \
    _Pragma("unroll")                                                       \
    for (int r = 0; r < 2; ++r) {                                           \
        int n_ = nh + r;                                                    \
        bh8 pd;                                                             \
        _Pragma("unroll")                                                   \
        for (int j = 0; j < 8; ++j)                                         \
            pd[j] = (short)f2bf(r ? wDr[j].y : wDr[j].x);                   \
        *(bh8*)(Db + swz(n_, kc * 16)) = pd;                                \
    } }

#define LOADX2(KT, XB) {                                                    \
    unsigned kby_ = (unsigned)(KT) * 128;                                   \
    _Pragma("unroll")                                                       \
    for (int i = 0; i < 4; ++i)                                             \
        gload16(actc + (size_t)aoff[i] + kby_, (XB) + i * 4096 + wv * 1024);\
    }

    LOADW2(0);
    LOADX2(0, Xb0);
    WRITEW2();
    __syncthreads();

    const int NT = IDIM / BK;
    for (int kt = 0; kt < NT; ++kt) {
        char* cur = (kt & 1) ? Xb1 : Xb0;
        char* nxt = (kt & 1) ? Xb0 : Xb1;
        if (kt < NT - 1) {
            LOADW2(kt + 1);
            LOADX2(kt + 1, nxt);
        }
#pragma unroll
        for (int ks = 0; ks < 2; ++ks) {
            int kb = ks * 64 + ((l >> 4) << 4);
            bh8 a[2], b[4];
#pragma unroll
            for (int mi = 0; mi < 2; ++mi)
                a[mi] = *(const bh8*)(cur + swz(wv * 32 + mi * 16 + (l & 15), kb));
#pragma unroll
            for (int ni = 0; ni < 4; ++ni)
                b[ni] = *(const bh8*)(Db + swz(ni * 16 + (l & 15), kb));
#pragma unroll
            for (int mi = 0; mi < 2; ++mi)
#pragma unroll
                for (int ni = 0; ni < 4; ++ni)
                    acc[mi][ni] = __builtin_amdgcn_mfma_f32_16x16x32_bf16(a[mi], b[ni], acc[mi][ni], 0, 0, 0);
        }
        __syncthreads();
        if (kt < NT - 1) {
            WRITEW2();
            __syncthreads();
        }
    }

    // epilogue: scale by routing weight, atomic accumulate
#pragma unroll
    for (int mi = 0; mi < 2; ++mi) {
#pragma unroll
        for (int i = 0; i < 4; ++i) {
            int r = rt * BM + wv * 32 + mi * 16 + ((l >> 4) << 2) + i;
            int tok = row_tok[r];
            if (tok < 0) continue;
            float w = row_w[r];
            float* op = out + (size_t)tok * HDIM + nt * 64 + (l & 15);
#pragma unroll
            for (int ni = 0; ni < 4; ++ni)
                atomicAdd(op + ni * 16, acc[mi][ni][i] * w);
        }
    }
#undef LOADW2
#undef WRITEW2
#undef LOADX2
}

// ---------------- launch ----------------
// ws layout:
//   [0,512): counts(128) | cursor(128) | offs(132)
//   512:           row_tok  CAP*4
//   512+CAP*4:     row_w    CAP*4
//   512+CAP*8:     act      CAP*IDIM*2   (41.9 MB)
//   +actB:         hs_bf16  T*H*2        (33.6 MB)
//   total ~75.7 MB

extern "C" void kernel_launch(void* const* d_in, const int* in_sizes, int n_in,
                              void* d_out, int out_size, void* d_ws, size_t ws_size,
                              hipStream_t stream) {
    const float* hs     = (const float*)d_in[0];
    const float* logits = (const float*)d_in[1];
    const float* scale  = (const float*)d_in[2];
    const float* wg     = (const float*)d_in[3];
    const float* wu     = (const float*)d_in[4];
    const float* wd     = (const float*)d_in[5];
    float* out = (float*)d_out;

    char* ws = (char*)d_ws;
    int*   counts  = (int*)ws;
    int*   cursor  = counts + 32;
    int*   offs    = cursor + 32;
    int*   row_tok = (int*)(ws + 512);
    float* row_w   = (float*)(ws + 512 + (size_t)CAP * 4);
    unsigned short* act = (unsigned short*)(ws + 512 + (size_t)CAP * 8);
    size_t actB = (size_t)CAP * IDIM * 2;
    unsigned short* hsb = (unsigned short*)(ws + 512 + (size_t)CAP * 8 + actB);

    hipMemsetAsync(counts, 0, 512, stream);
    hipMemsetAsync(row_tok, 0xFF, (size_t)CAP * 4, stream);
    hipMemsetAsync(out, 0, (size_t)out_size * sizeof(float), stream);

    route_count_kernel<<<T_TOK / 256, 256, 0, stream>>>(logits, counts);
    offsets_kernel<<<1, 64, 0, stream>>>(counts, offs);
    route_scatter_kernel<<<T_TOK / 256, 256, 0, stream>>>(logits, scale, offs, cursor, row_tok, row_w);
    cvt_hs_kernel<<<(T_TOK * HDIM) / (256 * 8), 256, 0, stream>>>(hs, hsb);
    gemm1f2_kernel<<<MAX_RT * 16, 256, 0, stream>>>(hsb, wg, wu, offs, row_tok, act);
    gemm2f2_kernel<<<MAX_RT * 32, 256, 0, stream>>>(act, wd, offs, row_tok, row_w, out);
}

// Round 5
// 695.437 us; speedup vs baseline: 3.0482x; 1.0758x over previous
//
#include <hip/hip_runtime.h>

#define T_TOK 8192
#define HDIM  2048
#define NEXP  32
#define IDIM  1024

#define BM 256
#define BK 64
#define CAP (T_TOK*2 + NEXP*BM)   // 24576 max padded rows
#define MAX_RT (CAP/BM)           // 96 row tiles max

typedef __attribute__((ext_vector_type(8))) short bh8;   // 8 bf16 (4 VGPR) MFMA A/B frag
typedef __attribute__((ext_vector_type(4))) float f4;    // MFMA C/D frag

// fp32 -> bf16 round-to-nearest-even (bit pattern)
__device__ __forceinline__ unsigned short f2bf(float f) {
    unsigned u = __builtin_bit_cast(unsigned, f);
    u += 0x7FFFu + ((u >> 16) & 1u);
    return (unsigned short)(u >> 16);
}

// X-buffer swizzle (gload16 pre-swizzled-source pattern): byte ^= (row&7)<<4
__device__ __forceinline__ int swz(int row, int kb) {
    return row * 128 + (kb ^ ((row & 7) << 4));
}
// W-buffer swizzle (reg-staged, thread owns n-pair): byte ^= ((row>>1)&7)<<4.
// Write: quarter-wave slots = w ^ (l&7) -> 8 distinct, 2-way. Read: (nr>>1)&7
// spans 8 over 16 lanes, 2-way. Both free (m136).
__device__ __forceinline__ int swzG(int row, int kb) {
    return row * 128 + (kb ^ (((row >> 1) & 7) << 4));
}

// async 16B global->LDS (dest = wave-uniform base + lane*16, source per-lane)
__device__ __forceinline__ void gload16(const void* g, void* l) {
    __builtin_amdgcn_global_load_lds(
        (const __attribute__((address_space(1))) unsigned int*)g,
        (__attribute__((address_space(3))) unsigned int*)l,
        16, 0, 0);
}

// ---------------- routing ----------------

__device__ __forceinline__ void top2(const float* __restrict__ l,
                                     int& b1, float& v1, int& b2, float& v2) {
    v1 = -1e30f; b1 = 0;
#pragma unroll
    for (int e = 0; e < NEXP; ++e) { float v = l[e]; if (v > v1) { v1 = v; b1 = e; } }
    v2 = -1e30f; b2 = 0;
#pragma unroll
    for (int e = 0; e < NEXP; ++e) { if (e == b1) continue; float v = l[e]; if (v > v2) { v2 = v; b2 = e; } }
}

__global__ void route_count_kernel(const float* __restrict__ logits, int* __restrict__ counts) {
    int t = blockIdx.x * blockDim.x + threadIdx.x;
    if (t >= T_TOK) return;
    int b1, b2; float v1, v2;
    top2(logits + (size_t)t * NEXP, b1, v1, b2, v2);
    atomicAdd(&counts[b1], 1);
    atomicAdd(&counts[b2], 1);
}

__global__ void offsets_kernel(const int* __restrict__ counts, int* __restrict__ offs) {
    if (threadIdx.x == 0) {
        int o = 0;
        for (int e = 0; e < NEXP; ++e) { offs[e] = o; o += (counts[e] + BM - 1) & ~(BM - 1); }
        offs[NEXP] = o;
    }
}

__global__ void route_scatter_kernel(const float* __restrict__ logits,
                                     const float* __restrict__ scale,
                                     const int* __restrict__ offs,
                                     int* __restrict__ cursor,
                                     int* __restrict__ row_tok,
                                     float* __restrict__ row_w) {
    int t = blockIdx.x * blockDim.x + threadIdx.x;
    if (t >= T_TOK) return;
    int b1, b2; float v1, v2;
    top2(logits + (size_t)t * NEXP, b1, v1, b2, v2);
    float e2 = expf(v2 - v1);
    float inv = 1.0f / (1.0f + e2);
    float w1 = scale[b1] * inv;
    float w2 = scale[b2] * e2 * inv;
    int p1 = offs[b1] + atomicAdd(&cursor[b1], 1);
    row_tok[p1] = t; row_w[p1] = w1;
    int p2 = offs[b2] + atomicAdd(&cursor[b2], 1);
    row_tok[p2] = t; row_w[p2] = w2;
}

// hs fp32 -> bf16 streaming convert
__global__ void cvt_hs_kernel(const float* __restrict__ in, unsigned short* __restrict__ out) {
    size_t i = ((size_t)blockIdx.x * 256 + threadIdx.x) * 8;
    float4 a = *(const float4*)(in + i);
    float4 b = *(const float4*)(in + i + 4);
    bh8 v;
    v[0] = (short)f2bf(a.x); v[1] = (short)f2bf(a.y);
    v[2] = (short)f2bf(a.z); v[3] = (short)f2bf(a.w);
    v[4] = (short)f2bf(b.x); v[5] = (short)f2bf(b.y);
    v[6] = (short)f2bf(b.z); v[7] = (short)f2bf(b.w);
    *(bh8*)(out + i) = v;
}

// ============ GEMM1: act = gelu(X@Wg) * (X@Wu), fused fp32-W convert ============
// 512 threads, 256 rows x 128 cols (G and U each). Waves 4m x 2n, wave=64x64 dual.
// X: bf16 gload16 dbuf. Wg/Wu: fp32 [k][n] -> float2 reg stage -> bf16 swzG LDS dbuf.
// ONE barrier per K-tile.
__launch_bounds__(512, 2)
__global__ void gemm1v5(const unsigned short* __restrict__ hsb,
                        const float* __restrict__ wg,
                        const float* __restrict__ wu,
                        const int* __restrict__ offs,
                        const int* __restrict__ row_tok,
                        unsigned short* __restrict__ act) {
    __shared__ char lds[131072];
    // X0 @0 (32K) | X1 @32768 | G0 @65536 (16K) | G1 @81920 | U0 @98304 | U1 @114688

    int rt = blockIdx.x >> 3;
    int nt = blockIdx.x & 7;          // IDIM/128
    if (rt * BM >= offs[NEXP]) return;
    int e = 0;
    while (offs[e + 1] <= rt * BM) e++;

    int tid = threadIdx.x, l = tid & 63, w = tid >> 6;
    int wm = w >> 1, wn = w & 1;

    // ---- X staging (gload16, pre-swizzled source) ----
    unsigned srcx = ((l & 7) * 16) ^ ((l >> 3) << 4);
    size_t xoff[4];
#pragma unroll
    for (int i = 0; i < 4; ++i) {
        int tok = row_tok[rt * BM + i * 64 + w * 8 + (l >> 3)];
        if (tok < 0) tok = 0;
        xoff[i] = (size_t)tok * (HDIM * 2) + srcx;
    }
    const char* hsc = (const char*)hsb;

    // ---- W staging: thread owns n-pair (2np,2np+1), 8 consecutive k (w*8+j) ----
    int np = tid & 63;
    const float* wg0 = wg + (size_t)e * HDIM * IDIM + (size_t)w * 8 * IDIM + nt * 128 + 2 * np;
    const float* wu0 = wu + (size_t)e * HDIM * IDIM + (size_t)w * 8 * IDIM + nt * 128 + 2 * np;
    float2 wgr[8], wur[8];
    int wb0 = swzG(2 * np, w * 16);
    int wb1 = swzG(2 * np + 1, w * 16);

    f4 accG[4][4], accU[4][4];
#pragma unroll
    for (int mi = 0; mi < 4; ++mi)
#pragma unroll
        for (int ni = 0; ni < 4; ++ni) { accG[mi][ni] = (f4)0.0f; accU[mi][ni] = (f4)0.0f; }

#define LOADW(KT) {                                                         \
    const float* gp_ = wg0 + (size_t)(KT) * 64 * IDIM;                      \
    const float* up_ = wu0 + (size_t)(KT) * 64 * IDIM;                      \
    _Pragma("unroll")                                                       \
    for (int j = 0; j < 8; ++j) {                                           \
        wgr[j] = *(const float2*)(gp_ + (size_t)j * IDIM);                  \
        wur[j] = *(const float2*)(up_ + (size_t)j * IDIM);                  \
    } }

#define WRITEW(GD, UD) {                                                    \
    bh8 p0, p1, q0, q1;                                                     \
    _Pragma("unroll")                                                       \
    for (int j = 0; j < 8; ++j) {                                           \
        p0[j] = (short)f2bf(wgr[j].x); p1[j] = (short)f2bf(wgr[j].y);       \
        q0[j] = (short)f2bf(wur[j].x); q1[j] = (short)f2bf(wur[j].y);       \
    }                                                                       \
    *(bh8*)((GD) + wb0) = p0; *(bh8*)((GD) + wb1) = p1;                     \
    *(bh8*)((UD) + wb0) = q0; *(bh8*)((UD) + wb1) = q1;                     \
    }

#define LOADX(KT, XD) {                                                     \
    size_t kby_ = (size_t)(KT) * 128;                                       \
    _Pragma("unroll")                                                       \
    for (int i = 0; i < 4; ++i)                                             \
        gload16(hsc + xoff[i] + kby_, (XD) + i * 8192 + w * 1024);          \
    }

    // prologue: tile 0
    LOADW(0);
    LOADX(0, lds);
    WRITEW(lds + 65536, lds + 98304);
    __syncthreads();

    const int NT = HDIM / BK;   // 32
    for (int kt = 0; kt < NT; ++kt) {
        char* Xc = (kt & 1) ? (lds + 32768) : lds;
        char* Xn = (kt & 1) ? lds : (lds + 32768);
        char* Gc = (kt & 1) ? (lds + 81920) : (lds + 65536);
        char* Gn = (kt & 1) ? (lds + 65536) : (lds + 81920);
        char* Uc = (kt & 1) ? (lds + 114688) : (lds + 98304);
        char* Un = (kt & 1) ? (lds + 98304) : (lds + 114688);

        if (kt < NT - 1) {
            LOADW(kt + 1);          // fp32 W -> regs (lands under compute)
            LOADX(kt + 1, Xn);      // bf16 X -> other LDS buf (async DMA)
        }
#pragma unroll
        for (int ks = 0; ks < 2; ++ks) {
            int kb = ks * 64 + ((l >> 4) << 4);
            bh8 a[4], g[4], u[4];
#pragma unroll
            for (int mi = 0; mi < 4; ++mi)
                a[mi] = *(const bh8*)(Xc + swz(wm * 64 + mi * 16 + (l & 15), kb));
#pragma unroll
            for (int ni = 0; ni < 4; ++ni) {
                int nr = wn * 64 + ni * 16 + (l & 15);
                g[ni] = *(const bh8*)(Gc + swzG(nr, kb));
                u[ni] = *(const bh8*)(Uc + swzG(nr, kb));
            }
#pragma unroll
            for (int mi = 0; mi < 4; ++mi)
#pragma unroll
                for (int ni = 0; ni < 4; ++ni) {
                    accG[mi][ni] = __builtin_amdgcn_mfma_f32_16x16x32_bf16(a[mi], g[ni], accG[mi][ni], 0, 0, 0);
                    accU[mi][ni] = __builtin_amdgcn_mfma_f32_16x16x32_bf16(a[mi], u[ni], accU[mi][ni], 0, 0, 0);
                }
        }
        if (kt < NT - 1) WRITEW(Gn, Un);   // convert + write next W tile
        __syncthreads();                   // drains vmcnt (X dma) + lgkm (W writes)
    }

    // epilogue: gelu(g)*u -> bf16 act, pre-swizzled byte layout
    char* actc = (char*)act;
#pragma unroll
    for (int mi = 0; mi < 4; ++mi) {
#pragma unroll
        for (int i = 0; i < 4; ++i) {
            int r = rt * BM + wm * 64 + mi * 16 + ((l >> 4) << 2) + i;
            size_t rowbase = (size_t)r * (IDIM * 2);
            int rs = (r & 7) << 4;
#pragma unroll
            for (int ni = 0; ni < 4; ++ni) {
                int col = nt * 128 + wn * 64 + ni * 16 + (l & 15);
                float gv = accG[mi][ni][i], uv = accU[mi][ni][i];
                float gl = 0.5f * gv * (1.0f + erff(gv * 0.70710678118654752f));
                *(unsigned short*)(actc + rowbase + ((col * 2) ^ rs)) = f2bf(gl * uv);
            }
        }
    }
#undef LOADW
#undef WRITEW
#undef LOADX
}

// ============ GEMM2: out[tok] += w * (act @ Wd), fused fp32-W convert ============
// 512 threads, 256 rows x 256 cols. Waves 4m x 2n, wave=64x128. act: gload16 dbuf
// (pre-swizzled rows -> linear source). Wd: fp32 float2 reg stage -> swzG LDS dbuf.
__launch_bounds__(512, 2)
__global__ void gemm2v5(const unsigned short* __restrict__ act,
                        const float* __restrict__ wd,
                        const int* __restrict__ offs,
                        const int* __restrict__ row_tok,
                        const float* __restrict__ row_w,
                        float* __restrict__ out) {
    __shared__ char lds[131072];
    // X0 @0 (32K) | X1 @32768 | D0 @65536 (32K) | D1 @98304

    int rt = blockIdx.x >> 3;
    int nt = blockIdx.x & 7;          // HDIM/256
    if (rt * BM >= offs[NEXP]) return;
    int e = 0;
    while (offs[e + 1] <= rt * BM) e++;

    int tid = threadIdx.x, l = tid & 63, w = tid >> 6;
    int wm = w >> 1, wn = w & 1;

    size_t aoff[4];
#pragma unroll
    for (int i = 0; i < 4; ++i)
        aoff[i] = (size_t)(rt * BM + i * 64 + w * 8 + (l >> 3)) * (IDIM * 2) + (l & 7) * 16;
    const char* actc = (const char*)act;

    // Wd staging: thread owns n-pair (2np2, 2np2+1), 16 consecutive k (kh*16+j)
    int np2 = tid & 127;
    int kh = tid >> 7;                 // 0..3, wave-uniform (= w>>1)
    const float* wd0 = wd + (size_t)e * IDIM * HDIM + (size_t)kh * 16 * HDIM + nt * 256 + 2 * np2;
    float2 wdr[16];
    int db0 = swzG(2 * np2, kh * 32);
    int db1 = swzG(2 * np2 + 1, kh * 32);
    int db2 = swzG(2 * np2, kh * 32 + 16);
    int db3 = swzG(2 * np2 + 1, kh * 32 + 16);

    f4 acc[4][8];
#pragma unroll
    for (int mi = 0; mi < 4; ++mi)
#pragma unroll
        for (int ni = 0; ni < 8; ++ni) acc[mi][ni] = (f4)0.0f;

#define LOADD(KT) {                                                         \
    const float* dp_ = wd0 + (size_t)(KT) * 64 * HDIM;                      \
    _Pragma("unroll")                                                       \
    for (int j = 0; j < 16; ++j)                                            \
        wdr[j] = *(const float2*)(dp_ + (size_t)j * HDIM);                  \
    }

#define WRITED(DD) {                                                        \
    bh8 c0, c1, c2, c3;                                                     \
    _Pragma("unroll")                                                       \
    for (int j = 0; j < 8; ++j) {                                           \
        c0[j] = (short)f2bf(wdr[j].x);     c1[j] = (short)f2bf(wdr[j].y);   \
        c2[j] = (short)f2bf(wdr[8 + j].x); c3[j] = (short)f2bf(wdr[8 + j].y); \
    }                                                                       \
    *(bh8*)((DD) + db0) = c0; *(bh8*)((DD) + db1) = c1;                     \
    *(bh8*)((DD) + db2) = c2; *(bh8*)((DD) + db3) = c3;                     \
    }

#define LOADA(KT, XD) {                                                     \
    size_t kby_ = (size_t)(KT) * 128;                                       \
    _Pragma("unroll")                                                       \
    for (int i = 0; i < 4; ++i)                                             \
        gload16(actc + aoff[i] + kby_, (XD) + i * 8192 + w * 1024);         \
    }

    LOADD(0);
    LOADA(0, lds);
    WRITED(lds + 65536);
    __syncthreads();

    const int NT = IDIM / BK;   // 16
    for (int kt = 0; kt < NT; ++kt) {
        char* Xc = (kt & 1) ? (lds + 32768) : lds;
        char* Xn = (kt & 1) ? lds : (lds + 32768);
        char* Dc = (kt & 1) ? (lds + 98304) : (lds + 65536);
        char* Dn = (kt & 1) ? (lds + 65536) : (lds + 98304);

        if (kt < NT - 1) {
            LOADD(kt + 1);
            LOADA(kt + 1, Xn);
        }
#pragma unroll
        for (int ks = 0; ks < 2; ++ks) {
            int kb = ks * 64 + ((l >> 4) << 4);
            bh8 a[4], b[8];
#pragma unroll
            for (int mi = 0; mi < 4; ++mi)
                a[mi] = *(const bh8*)(Xc + swz(wm * 64 + mi * 16 + (l & 15), kb));
#pragma unroll
            for (int ni = 0; ni < 8; ++ni)
                b[ni] = *(const bh8*)(Dc + swzG(wn * 128 + ni * 16 + (l & 15), kb));
#pragma unroll
            for (int mi = 0; mi < 4; ++mi)
#pragma unroll
                for (int ni = 0; ni < 8; ++ni)
                    acc[mi][ni] = __builtin_amdgcn_mfma_f32_16x16x32_bf16(a[mi], b[ni], acc[mi][ni], 0, 0, 0);
        }
        if (kt < NT - 1) WRITED(Dn);
        __syncthreads();
    }

    // epilogue: scale by routing weight, atomic accumulate
#pragma unroll
    for (int mi = 0; mi < 4; ++mi) {
#pragma unroll
        for (int i = 0; i < 4; ++i) {
            int r = rt * BM + wm * 64 + mi * 16 + ((l >> 4) << 2) + i;
            int tok = row_tok[r];
            if (tok < 0) continue;
            float wgt = row_w[r];
            float* op = out + (size_t)tok * HDIM + nt * 256 + wn * 128 + (l & 15);
#pragma unroll
            for (int ni = 0; ni < 8; ++ni)
                atomicAdd(op + ni * 16, acc[mi][ni][i] * wgt);
        }
    }
#undef LOADD
#undef WRITED
#undef LOADA
}

// ---------------- launch ----------------
// ws layout:
//   [0,512): counts(128) | cursor(128) | offs(132)
//   512:           row_tok  CAP*4      (98 KB)
//   512+CAP*4:     row_w    CAP*4
//   512+CAP*8:     act      CAP*IDIM*2 (50.3 MB)
//   +actB:         hs_bf16  T*H*2      (33.6 MB)
//   total ~84.1 MB

extern "C" void kernel_launch(void* const* d_in, const int* in_sizes, int n_in,
                              void* d_out, int out_size, void* d_ws, size_t ws_size,
                              hipStream_t stream) {
    const float* hs     = (const float*)d_in[0];
    const float* logits = (const float*)d_in[1];
    const float* scale  = (const float*)d_in[2];
    const float* wg     = (const float*)d_in[3];
    const float* wu     = (const float*)d_in[4];
    const float* wd     = (const float*)d_in[5];
    float* out = (float*)d_out;

    char* ws = (char*)d_ws;
    int*   counts  = (int*)ws;
    int*   cursor  = counts + 32;
    int*   offs    = cursor + 32;
    int*   row_tok = (int*)(ws + 512);
    float* row_w   = (float*)(ws + 512 + (size_t)CAP * 4);
    unsigned short* act = (unsigned short*)(ws + 512 + (size_t)CAP * 8);
    size_t actB = (size_t)CAP * IDIM * 2;
    unsigned short* hsb = (unsigned short*)(ws + 512 + (size_t)CAP * 8 + actB);

    hipMemsetAsync(counts, 0, 512, stream);
    hipMemsetAsync(row_tok, 0xFF, (size_t)CAP * 4, stream);
    hipMemsetAsync(out, 0, (size_t)out_size * sizeof(float), stream);

    route_count_kernel<<<T_TOK / 256, 256, 0, stream>>>(logits, counts);
    offsets_kernel<<<1, 64, 0, stream>>>(counts, offs);
    route_scatter_kernel<<<T_TOK / 256, 256, 0, stream>>>(logits, scale, offs, cursor, row_tok, row_w);
    cvt_hs_kernel<<<(T_TOK * HDIM) / (256 * 8), 256, 0, stream>>>(hs, hsb);
    gemm1v5<<<MAX_RT * 8, 512, 0, stream>>>(hsb, wg, wu, offs, row_tok, act);
    gemm2v5<<<MAX_RT * 8, 512, 0, stream>>>(act, wd, offs, row_tok, row_w, out);
}